// Round 6
// baseline (79.953 us; speedup 1.0000x reference)
//
#include <hip/hip_runtime.h>
#include <stdint.h>

#define BB 256
#define CC 64
#define CVV 4
#define LL 2048

#define WAITV(n) asm volatile("s_waitcnt vmcnt(" #n ")" ::: "memory")

__device__ __forceinline__ void ce_desc(unsigned long long* key, int i, int j,
                                        bool descBlk) {
  unsigned long long a = key[i], c = key[j];
  bool sw = descBlk ? (a < c) : (a > c);
  if (sw) { key[i] = c; key[j] = a; }
}

// ---------------------------------------------------------------------------
// Kernel 1: per-batch stable descending argsort of rand_f via bitonic sort of
// 64-bit composite keys (ord(rand_f)<<32 | (L-1-idx)) in LDS, wave-segment
// optimized (stride<=128 substages are wave-local; ~10 block barriers total).
// Mask layout self-detected per block from a disjoint 512-word slice.
// Writes stage ints (idx | masked<<11 | keep<<12) vectorized int4, and the
// final mask_t floats (float4) when mout != nullptr.
// ---------------------------------------------------------------------------
__global__ __launch_bounds__(512) void sortperm_kernel(const void* mask,
                                                       const float* rnd,
                                                       int* stage,
                                                       float* mout) {
  __shared__ unsigned long long key[LL];
  __shared__ int cnt;
  __shared__ unsigned detf;
  const int b = blockIdx.x;
  const int tid = threadIdx.x;
  if (tid == 0) { cnt = 0; detf = 0; }
  __syncthreads();

  {
    unsigned val = ((const unsigned*)mask)[b * 512 + tid];
    unsigned f = (val == 0x3F800000u) ? 2u : (val > 1u ? 1u : 0u);
    if (f) atomicOr(&detf, f);
  }
  __syncthreads();
  const unsigned fl = detf;
  const int layout = (fl & 1u) ? 1 : ((fl & 2u) ? 2 : 0);

  int local = 0;
  for (int l = tid; l < LL; l += 512) {
    bool m;
    if (layout == 1)      m = ((const unsigned char*)mask)[b * LL + l] != 0;
    else if (layout == 2) m = ((const float*)mask)[b * LL + l] != 0.0f;
    else                  m = ((const int*)mask)[b * LL + l] != 0;
    float rf = m ? -1.0f : rnd[b * LL + l];
    unsigned u = __float_as_uint(rf);
    u = (u & 0x80000000u) ? ~u : (u | 0x80000000u);  // order-preserving map
    key[l] = ((unsigned long long)u << 32) | (unsigned)(LL - 1 - l);
    local += m ? 1 : 0;
  }
  if (local) atomicAdd(&cnt, local);
  __syncthreads();

  const int w = tid >> 6;    // wave id 0..7 owns key[w*256 .. w*256+255]
  const int lane = tid & 63;

  for (int size = 2; size <= 256; size <<= 1) {
    for (int stride = size >> 1; stride > 0; stride >>= 1) {
#pragma unroll
      for (int pp = 0; pp < 2; ++pp) {
        int p = w * 128 + pp * 64 + lane;
        int i = ((p & ~(stride - 1)) << 1) | (p & (stride - 1));
        ce_desc(key, i, i + stride, (i & size) == 0);
      }
      __builtin_amdgcn_wave_barrier();
    }
  }
  __syncthreads();

  for (int size = 512; size <= 2048; size <<= 1) {
    for (int stride = size >> 1; stride >= 256; stride >>= 1) {
      for (int t = tid; t < LL / 2; t += 512) {
        int i = ((t & ~(stride - 1)) << 1) | (t & (stride - 1));
        ce_desc(key, i, i + stride, (i & size) == 0);
      }
      __syncthreads();
    }
    for (int stride = 128; stride > 0; stride >>= 1) {
#pragma unroll
      for (int pp = 0; pp < 2; ++pp) {
        int p = w * 128 + pp * 64 + lane;
        int i = ((p & ~(stride - 1)) << 1) | (p & (stride - 1));
        ce_desc(key, i, i + stride, (i & size) == 0);
      }
      __builtin_amdgcn_wave_barrier();
    }
    __syncthreads();
  }

  const int maxlen = cnt > 1 ? cnt : 1;              // jnp.maximum(count, 1)
  const unsigned ordNeg1 = ~__float_as_uint(-1.0f);  // ord(-1.0)
  int sv[4];
  float mf[4];
#pragma unroll
  for (int k = 0; k < 4; ++k) {
    int j = tid * 4 + k;
    unsigned long long k2 = key[j];
    int idx = (LL - 1) - (int)(unsigned)(k2 & 0xFFFFFFFFull);
    bool masked = ((unsigned)(k2 >> 32)) == ordNeg1;
    bool keep = j < maxlen;
    sv[k] = idx | (masked ? (1 << 11) : 0) | (keep ? (1 << 12) : 0);
    mf[k] = (keep && masked) ? 1.0f : 0.0f;
  }
  ((int4*)(stage + (size_t)b * LL))[tid] = make_int4(sv[0], sv[1], sv[2], sv[3]);
  if (mout)
    ((float4*)(mout + (size_t)b * LL))[tid] =
        make_float4(mf[0], mf[1], mf[2], mf[3]);
}

// ---------------------------------------------------------------------------
// Kernel 2: wave-autonomous gather. Block = (batch b, quarter c), 4 waves;
// wave k = c*4+w owns x-rows 4k..4k+3 (+ v-row k when k<4). Each wave loads
// its own full 8 KB row with 8x global_load_lds(dwordx4) into a private
// 2-slot LDS double buffer, gathers via ds_read, stores coalesced float4 —
// ZERO barriers, zero cross-wave coupling; every wave is a self-paced
// load->LDS->store stream (the fill kernel proves deep queues at low
// occupancy saturate HBM). Counted vmcnt (in-order per-wave VMEM retire):
// steady queue before gather(i) = [L(i)x8, S(i-1)x8, L(i+1)x8] -> vmcnt(16);
// first/last rows 8. Slot reuse is intra-wave program-ordered (ds_reads of a
// slot are consumed into registers before the overwriting loads issue).
// ---------------------------------------------------------------------------
__global__ __launch_bounds__(256) void gather_kernel(
    const float* __restrict__ x, const float* __restrict__ v,
    const int* __restrict__ stage, float* __restrict__ xo,
    float* __restrict__ vo) {
  __shared__ float ring[4][2][LL];  // 64 KB: [wave][slot][elem]
  const int swz = (blockIdx.x & 7) * 128 + (blockIdx.x >> 3);  // XCD-chunked
  const int b = swz >> 2;
  const int c = swz & 3;
  const int w = threadIdx.x >> 6;
  const int lane = threadIdx.x & 63;
  const int k = c * 4 + w;                 // wave index in batch, 0..15
  const int nrows = (k < 4) ? 5 : 4;       // 4 x-rows + maybe 1 v-row

  // perm entries for this lane's 8 output float4 chunks (coalesced int4)
  const int4* st4 = (const int4*)(stage + (size_t)b * LL);
  int4 s[8];
#pragma unroll
  for (int q = 0; q < 8; ++q) s[q] = st4[lane + 64 * q];

  const float* const xs = x + (size_t)b * CC * LL;
  const float* const vs = v + (size_t)b * CVV * LL;
  float* const xd = xo + (size_t)b * CC * LL;
  float* const vd = vo + (size_t)b * CVV * LL;
  float* const myring = &ring[w][0][0];

#define SRCROW(i) ((i) < 4 ? xs + (size_t)(4 * k + (i)) * LL \
                           : vs + (size_t)k * LL)
#define DSTROW(i) ((i) < 4 ? xd + (size_t)(4 * k + (i)) * LL \
                           : vd + (size_t)k * LL)

  // 8 async 1 KB ops load one full row into slot: LDS dest wave-uniform,
  // global src per-lane (src + n*256 + lane*4 floats).
#define ISSUE(i, slot) do { \
    const float* _src = SRCROW(i) + lane * 4; \
    float* _dst = myring + (slot) * LL; \
    _Pragma("unroll") \
    for (int n = 0; n < 8; ++n) { \
      __builtin_amdgcn_global_load_lds( \
          (const __attribute__((address_space(1))) void*)(_src + n * 256), \
          (__attribute__((address_space(3))) void*)(_dst + n * 256), 16, 0, 0); \
    } \
  } while (0)

  ISSUE(0, 0);

#pragma unroll 1
  for (int i = 0; i < nrows; ++i) {
    if (i + 1 < nrows) ISSUE(i + 1, (i + 1) & 1);
    if (i == 0 || i == nrows - 1) WAITV(8);
    else                          WAITV(16);

    const float* buf = myring + (i & 1) * LL;
    float4* d4 = (float4*)DSTROW(i);
#pragma unroll
    for (int q = 0; q < 8; ++q) {
      float4 o;
      o.x = (s[q].x & (1 << 12)) ? buf[s[q].x & 0x7FF] : 0.0f;
      o.y = (s[q].y & (1 << 12)) ? buf[s[q].y & 0x7FF] : 0.0f;
      o.z = (s[q].z & (1 << 12)) ? buf[s[q].z & 0x7FF] : 0.0f;
      o.w = (s[q].w & (1 << 12)) ? buf[s[q].w & 0x7FF] : 0.0f;
      d4[lane + 64 * q] = o;
    }
  }
#undef ISSUE
#undef SRCROW
#undef DSTROW
}

// ---------------------------------------------------------------------------
// Kernel 3 (fallback only, when ws is too small and stage aliases the mask
// output): convert staged ints in place to the final mask floats.
// ---------------------------------------------------------------------------
__global__ __launch_bounds__(256) void maskout_kernel(int* stage,
                                                      float* mout) {
  const int i = blockIdx.x * 256 + threadIdx.x;
  int s = stage[i];
  mout[i] = ((s & (1 << 12)) && (s & (1 << 11))) ? 1.0f : 0.0f;
}

extern "C" void kernel_launch(void* const* d_in, const int* in_sizes, int n_in,
                              void* d_out, int out_size, void* d_ws, size_t ws_size,
                              hipStream_t stream) {
  const float* x    = (const float*)d_in[0];
  const float* v    = (const float*)d_in[1];
  const void*  mask = d_in[2];
  const float* rnd  = (const float*)d_in[3];

  float* xo = (float*)d_out;                  // B*C*L
  float* vo = xo + (size_t)BB * CC * LL;      // B*CV*L
  float* mo = vo + (size_t)BB * CVV * LL;     // B*1*L

  const bool use_ws = ws_size >= (size_t)BB * LL * sizeof(int);
  int* stage = use_ws ? (int*)d_ws : (int*)mo;

  sortperm_kernel<<<BB, 512, 0, stream>>>(mask, rnd, stage,
                                          use_ws ? mo : nullptr);
  gather_kernel<<<BB * 4, 256, 0, stream>>>(x, v, stage, xo, vo);
  if (!use_ws)
    maskout_kernel<<<(BB * LL) / 256, 256, 0, stream>>>(stage, mo);
}